// Round 1
// baseline (138.925 us; speedup 1.0000x reference)
//
#include <hip/hip_runtime.h>

#define NBINS 256

// cs[i] = clip(-1 + i/127, -1, 1) computed exactly as the reference (fp32 ops)
__device__ __forceinline__ float csv(int i) {
    float c = -1.0f + (float)i / 127.0f;
    return fminf(fmaxf(c, -1.0f), 1.0f);
}

// ---------------------------------------------------------------------------
// Kernel 1: histograms of src and tgt, 3 channels each -> ghist[6][256]
// Layout: element i of the flat (H*W*3) array belongs to channel i%3.
// ---------------------------------------------------------------------------
__global__ void hm_hist(const float* __restrict__ src, const float* __restrict__ tgt,
                        int n, int* __restrict__ ghist) {
    __shared__ int lh[6 * NBINS];
    for (int i = threadIdx.x; i < 6 * NBINS; i += blockDim.x) lh[i] = 0;
    __syncthreads();

    const int stride = gridDim.x * blockDim.x;
    for (int i = blockIdx.x * blockDim.x + threadIdx.x; i < n; i += stride) {
        int c = i % 3;
        float v = src[i];
        v = fminf(fmaxf(v, -1.0f), 1.0f);
        int b = (int)((v + 1.0f) * 128.0f);   // trunc toward zero, matches astype(int32)
        b = min(max(b, 0), NBINS - 1);
        atomicAdd(&lh[c * NBINS + b], 1);

        float w = tgt[i];
        w = fminf(fmaxf(w, -1.0f), 1.0f);
        int b2 = (int)((w + 1.0f) * 128.0f);
        b2 = min(max(b2, 0), NBINS - 1);
        atomicAdd(&lh[(3 + c) * NBINS + b2], 1);
    }
    __syncthreads();
    for (int i = threadIdx.x; i < 6 * NBINS; i += blockDim.x) {
        int v = lh[i];
        if (v) atomicAdd(&ghist[i], v);
    }
}

// ---------------------------------------------------------------------------
// Kernel 2: per-channel (blockIdx.x = channel): cumsum -> cdfsrc/cdftgt ->
// pxmap = _interpolate(cdftgt, cs, cdfsrc). 256 threads = 256 bins.
// ---------------------------------------------------------------------------
__global__ void hm_tables(const int* __restrict__ ghist, float pixcnt_m1,
                          float* __restrict__ pxmap) {
    const int c = blockIdx.x;
    const int t = threadIdx.x;
    __shared__ int ss[NBINS];
    __shared__ int st[NBINS];
    __shared__ float cdfs[NBINS];
    __shared__ float cdft[NBINS];

    ss[t] = ghist[c * NBINS + t];
    st[t] = ghist[(3 + c) * NBINS + t];
    __syncthreads();

    // Hillis-Steele inclusive scan for both histograms
    for (int off = 1; off < NBINS; off <<= 1) {
        int a = (t >= off) ? ss[t - off] : 0;
        int b = (t >= off) ? st[t - off] : 0;
        __syncthreads();
        ss[t] += a;
        st[t] += b;
        __syncthreads();
    }

    // cdf is nondecreasing -> min = cdf[0]
    int mins = ss[0];
    int mint = st[0];
    // exact op order: (float)(cdf - min) * 2.0f / (pixcnt-1) - 1.0f
    cdfs[t] = (float)(ss[t] - mins) * 2.0f / pixcnt_m1 - 1.0f;
    cdft[t] = (float)(st[t] - mint) * 2.0f / pixcnt_m1 - 1.0f;
    __syncthreads();

    // pxmap[t] = _interpolate(dx=cdftgt, dy=cs, x=cdfsrc[t])
    float x = cdfs[t];
    int ind1 = 0;
    float best = fabsf(cdft[0] - x);
    for (int i = 1; i < NBINS; i++) {
        float d = fabsf(cdft[i] - x);
        if (d < best) { best = d; ind1 = i; }   // strict < => first-min (argmin ties)
    }
    int ind0 = max(ind1 - 1, 0);
    float x0 = cdft[ind0], x1 = cdft[ind1];
    float y0 = csv(ind0),  y1 = csv(ind1);
    float denom = x1 - x0;
    float safe = (denom == 0.0f) ? 1.0f : denom;
    float interp = y0 + (y1 - y0) * (x - x0) / safe;

    float r;
    if (x <= cdft[0])            r = csv(0);
    else if (x >= cdft[NBINS-1]) r = csv(NBINS - 1);
    else                         r = interp;

    pxmap[c * NBINS + t] = r;
}

// ---------------------------------------------------------------------------
// Kernel 3: mapped = _interpolate(dx=cs, dy=pxmap[c], x=src pixel)
// cs is a uniform grid (spacing 1/127) with cs[254]==cs[255]==1.0; the argmin
// index is within +/-1 of the analytic estimate; resolve exactly with fp32
// distances scanned in ascending index order (strict <  => first-min).
// ---------------------------------------------------------------------------
__global__ void hm_map(const float* __restrict__ src, const float* __restrict__ pxmap,
                       float* __restrict__ out, int n) {
    __shared__ float pm[3 * NBINS];
    for (int i = threadIdx.x; i < 3 * NBINS; i += blockDim.x) pm[i] = pxmap[i];
    __syncthreads();

    const int stride = gridDim.x * blockDim.x;
    for (int i = blockIdx.x * blockDim.x + threadIdx.x; i < n; i += stride) {
        float x = src[i];
        int c = i % 3;
        const float* y = &pm[c * NBINS];
        float r;
        if (x <= -1.0f) {
            r = y[0];
        } else if (x >= 1.0f) {
            r = y[NBINS - 1];
        } else {
            float kf = (x + 1.0f) * 127.0f;
            int k = (int)(kf + 0.5f);
            int lo = max(k - 1, 0);
            int hi = min(k + 1, NBINS - 1);
            int ind1 = lo;
            float best = fabsf(csv(lo) - x);
            for (int j = lo + 1; j <= hi; j++) {
                float d = fabsf(csv(j) - x);
                if (d < best) { best = d; ind1 = j; }
            }
            int ind0 = max(ind1 - 1, 0);
            float x0 = csv(ind0), x1 = csv(ind1);
            float y0 = y[ind0],   y1 = y[ind1];
            float denom = x1 - x0;
            float safe = (denom == 0.0f) ? 1.0f : denom;
            r = y0 + (y1 - y0) * (x - x0) / safe;
        }
        out[i] = r;
    }
}

extern "C" void kernel_launch(void* const* d_in, const int* in_sizes, int n_in,
                              void* d_out, int out_size, void* d_ws, size_t ws_size,
                              hipStream_t stream) {
    const float* src = (const float*)d_in[0];
    const float* tgt = (const float*)d_in[1];
    float* out = (float*)d_out;

    const int n = in_sizes[0];          // H*W*3
    const int pixcnt = n / 3;           // H*W

    int*   ghist = (int*)d_ws;                      // 6*256 ints
    float* pxmap = (float*)((char*)d_ws + 6 * NBINS * sizeof(int)); // 3*256 floats

    hipMemsetAsync(ghist, 0, 6 * NBINS * sizeof(int), stream);

    const int threads = 256;
    int blocks = 2048;
    hm_hist<<<blocks, threads, 0, stream>>>(src, tgt, n, ghist);

    hm_tables<<<3, NBINS, 0, stream>>>(ghist, (float)pixcnt - 1.0f, pxmap);

    hm_map<<<4096, threads, 0, stream>>>(src, pxmap, out, n);
}

// Round 2
// 136.026 us; speedup vs baseline: 1.0213x; 1.0213x over previous
//
#include <hip/hip_runtime.h>

#define NBINS 256

// cs[i] = clip(-1 + i/127, -1, 1) computed exactly as the reference (fp32 ops)
__device__ __forceinline__ float csv(int i) {
    float c = -1.0f + (float)i / 127.0f;
    return fminf(fmaxf(c, -1.0f), 1.0f);
}

__device__ __forceinline__ int binof(float v) {
    v = fminf(fmaxf(v, -1.0f), 1.0f);
    int b = (int)((v + 1.0f) * 128.0f);   // trunc toward zero == astype(int32)
    return min(max(b, 0), NBINS - 1);
}

// ---------------------------------------------------------------------------
// Kernel 1: per-block private histograms (src ch0..2, tgt ch0..2) -> written
// NON-atomically to partials[blockIdx][6][256]. float4 streaming loads.
// Grid must be exactly NB blocks (each owns one partial slot).
// ---------------------------------------------------------------------------
__global__ __launch_bounds__(1024) void hm_hist(const float4* __restrict__ src4,
                                                const float4* __restrict__ tgt4,
                                                const float* __restrict__ src,
                                                const float* __restrict__ tgt,
                                                int n4, int n,
                                                int* __restrict__ partials) {
    __shared__ int lh[6 * NBINS];
    for (int i = threadIdx.x; i < 6 * NBINS; i += blockDim.x) lh[i] = 0;
    __syncthreads();

    const int stride = gridDim.x * blockDim.x;
    for (int i = blockIdx.x * blockDim.x + threadIdx.x; i < n4; i += stride) {
        // flat base index = 4*i; (4*i) % 3 == i % 3
        int c0 = i % 3;
        int c1 = c0 + 1; if (c1 == 3) c1 = 0;
        int c2 = c1 + 1; if (c2 == 3) c2 = 0;
        float4 s = src4[i];
        float4 t = tgt4[i];
        atomicAdd(&lh[c0 * NBINS + binof(s.x)], 1);
        atomicAdd(&lh[c1 * NBINS + binof(s.y)], 1);
        atomicAdd(&lh[c2 * NBINS + binof(s.z)], 1);
        atomicAdd(&lh[c0 * NBINS + binof(s.w)], 1);
        atomicAdd(&lh[(3 + c0) * NBINS + binof(t.x)], 1);
        atomicAdd(&lh[(3 + c1) * NBINS + binof(t.y)], 1);
        atomicAdd(&lh[(3 + c2) * NBINS + binof(t.z)], 1);
        atomicAdd(&lh[(3 + c0) * NBINS + binof(t.w)], 1);
    }
    // scalar tail (n not divisible by 4)
    if (blockIdx.x == 0) {
        int base = n4 * 4;
        int rem = n - base;
        if ((int)threadIdx.x < rem) {
            int j = base + threadIdx.x;
            int c = j % 3;
            atomicAdd(&lh[c * NBINS + binof(src[j])], 1);
            atomicAdd(&lh[(3 + c) * NBINS + binof(tgt[j])], 1);
        }
    }
    __syncthreads();

    int* dst = partials + blockIdx.x * 6 * NBINS;
    for (int i = threadIdx.x; i < 6 * NBINS; i += blockDim.x) dst[i] = lh[i];
}

// ---------------------------------------------------------------------------
// Kernel 2: per-channel (blockIdx.x = channel): reduce partials -> cumsum ->
// cdfsrc/cdftgt -> pxmap = _interpolate(cdftgt, cs, cdfsrc). 256 thr = 256 bins.
// ---------------------------------------------------------------------------
__global__ void hm_tables(const int* __restrict__ partials, int NB,
                          float pixcnt_m1, float* __restrict__ pxmap) {
    const int c = blockIdx.x;
    const int t = threadIdx.x;
    __shared__ int ss[NBINS];
    __shared__ int st[NBINS];
    __shared__ float cdfs[NBINS];
    __shared__ float cdft[NBINS];

    int as = 0, at = 0;
    for (int b = 0; b < NB; b++) {
        const int* p = partials + b * 6 * NBINS;
        as += p[c * NBINS + t];
        at += p[(3 + c) * NBINS + t];
    }
    ss[t] = as;
    st[t] = at;
    __syncthreads();

    // Hillis-Steele inclusive scan (both histograms)
    for (int off = 1; off < NBINS; off <<= 1) {
        int a = (t >= off) ? ss[t - off] : 0;
        int b = (t >= off) ? st[t - off] : 0;
        __syncthreads();
        ss[t] += a;
        st[t] += b;
        __syncthreads();
    }

    // cdf nondecreasing -> min = cdf[0]; exact ref op order
    int mins = ss[0];
    int mint = st[0];
    cdfs[t] = (float)(ss[t] - mins) * 2.0f / pixcnt_m1 - 1.0f;
    cdft[t] = (float)(st[t] - mint) * 2.0f / pixcnt_m1 - 1.0f;
    __syncthreads();

    // pxmap[t] = _interpolate(dx=cdftgt, dy=cs, x=cdfsrc[t]); first-min argmin
    float x = cdfs[t];
    int ind1 = 0;
    float best = fabsf(cdft[0] - x);
    for (int i = 1; i < NBINS; i++) {
        float d = fabsf(cdft[i] - x);
        if (d < best) { best = d; ind1 = i; }
    }
    int ind0 = max(ind1 - 1, 0);
    float x0 = cdft[ind0], x1 = cdft[ind1];
    float y0 = csv(ind0),  y1 = csv(ind1);
    float denom = x1 - x0;
    float safe = (denom == 0.0f) ? 1.0f : denom;
    float interp = y0 + (y1 - y0) * (x - x0) / safe;

    float r;
    if (x <= cdft[0])            r = csv(0);
    else if (x >= cdft[NBINS-1]) r = csv(NBINS - 1);
    else                         r = interp;

    pxmap[c * NBINS + t] = r;
}

// ---------------------------------------------------------------------------
// Kernel 3: mapped = _interpolate(dx=cs, dy=pxmap[c], x=src). float4 I/O.
// ---------------------------------------------------------------------------
__device__ __forceinline__ float map_one(float x, const float* __restrict__ y) {
    if (x <= -1.0f) return y[0];
    if (x >= 1.0f)  return y[NBINS - 1];
    float kf = (x + 1.0f) * 127.0f;
    int k = (int)(kf + 0.5f);
    int lo = max(k - 1, 0);
    int hi = min(k + 1, NBINS - 1);
    int ind1 = lo;
    float best = fabsf(csv(lo) - x);
    for (int j = lo + 1; j <= hi; j++) {
        float d = fabsf(csv(j) - x);
        if (d < best) { best = d; ind1 = j; }
    }
    int ind0 = max(ind1 - 1, 0);
    float x0 = csv(ind0), x1 = csv(ind1);
    float y0 = y[ind0],   y1 = y[ind1];
    float denom = x1 - x0;
    float safe = (denom == 0.0f) ? 1.0f : denom;
    return y0 + (y1 - y0) * (x - x0) / safe;
}

__global__ void hm_map(const float4* __restrict__ src4, const float* __restrict__ src,
                       const float* __restrict__ pxmap,
                       float4* __restrict__ out4, float* __restrict__ out,
                       int n4, int n) {
    __shared__ float pm[3 * NBINS];
    for (int i = threadIdx.x; i < 3 * NBINS; i += blockDim.x) pm[i] = pxmap[i];
    __syncthreads();

    const int stride = gridDim.x * blockDim.x;
    for (int i = blockIdx.x * blockDim.x + threadIdx.x; i < n4; i += stride) {
        int c0 = i % 3;
        int c1 = c0 + 1; if (c1 == 3) c1 = 0;
        int c2 = c1 + 1; if (c2 == 3) c2 = 0;
        float4 s = src4[i];
        float4 r;
        r.x = map_one(s.x, &pm[c0 * NBINS]);
        r.y = map_one(s.y, &pm[c1 * NBINS]);
        r.z = map_one(s.z, &pm[c2 * NBINS]);
        r.w = map_one(s.w, &pm[c0 * NBINS]);
        out4[i] = r;
    }
    // scalar tail
    if (blockIdx.x == 0) {
        int base = n4 * 4;
        int rem = n - base;
        if ((int)threadIdx.x < rem) {
            int j = base + threadIdx.x;
            int c = j % 3;
            out[j] = map_one(src[j], &pm[c * NBINS]);
        }
    }
}

extern "C" void kernel_launch(void* const* d_in, const int* in_sizes, int n_in,
                              void* d_out, int out_size, void* d_ws, size_t ws_size,
                              hipStream_t stream) {
    const float* src = (const float*)d_in[0];
    const float* tgt = (const float*)d_in[1];
    float* out = (float*)d_out;

    const int n  = in_sizes[0];     // H*W*3
    const int n4 = n / 4;
    const int pixcnt = n / 3;       // H*W

    // ws layout: [0, 4096): pxmap (3*256 floats); [4096, ...): partials
    float* pxmap   = (float*)d_ws;
    int*   partials = (int*)((char*)d_ws + 4096);

    const int slot_bytes = 6 * NBINS * (int)sizeof(int);   // 6 KiB per block
    int NB = 256;
    if (ws_size >= 4096 + (size_t)slot_bytes) {
        size_t avail = (ws_size - 4096) / slot_bytes;
        if (avail < (size_t)NB) NB = (int)avail;
    } else {
        NB = 1;  // degenerate but correct
    }

    hm_hist<<<NB, 1024, 0, stream>>>((const float4*)src, (const float4*)tgt,
                                     src, tgt, n4, n, partials);

    hm_tables<<<3, NBINS, 0, stream>>>(partials, NB, (float)pixcnt - 1.0f, pxmap);

    int mblocks = (n4 + 255) / 256;
    if (mblocks > 3072) mblocks = 3072;
    if (mblocks < 1) mblocks = 1;
    hm_map<<<mblocks, 256, 0, stream>>>((const float4*)src, src, pxmap,
                                        (float4*)out, out, n4, n);
}

// Round 3
// 100.481 us; speedup vs baseline: 1.3826x; 1.3537x over previous
//
#include <hip/hip_runtime.h>

#define NBINS 256
#define SLOT (6 * NBINS)   // ints per partial-histogram slot

// cs[i] = clip(-1 + i/127, -1, 1) computed exactly as the reference (fp32 ops)
__device__ __forceinline__ float csv(int i) {
    float c = -1.0f + (float)i / 127.0f;
    return fminf(fmaxf(c, -1.0f), 1.0f);
}

__device__ __forceinline__ int binof(float v) {
    v = fminf(fmaxf(v, -1.0f), 1.0f);
    int b = (int)((v + 1.0f) * 128.0f);   // trunc toward zero == astype(int32)
    return min(max(b, 0), NBINS - 1);
}

// ---------------------------------------------------------------------------
// Kernel 1: per-block private histograms (src ch0..2, tgt ch0..2) -> written
// NON-atomically to partials[blockIdx][6][256]. float4 streaming loads.
// Grid must be exactly NB blocks (each owns one partial slot).
// ---------------------------------------------------------------------------
__global__ __launch_bounds__(1024) void hm_hist(const float4* __restrict__ src4,
                                                const float4* __restrict__ tgt4,
                                                const float* __restrict__ src,
                                                const float* __restrict__ tgt,
                                                int n4, int n,
                                                int* __restrict__ partials) {
    __shared__ int lh[6 * NBINS];
    for (int i = threadIdx.x; i < 6 * NBINS; i += blockDim.x) lh[i] = 0;
    __syncthreads();

    const int stride = gridDim.x * blockDim.x;
    for (int i = blockIdx.x * blockDim.x + threadIdx.x; i < n4; i += stride) {
        // flat base index = 4*i; (4*i) % 3 == i % 3
        int c0 = i % 3;
        int c1 = c0 + 1; if (c1 == 3) c1 = 0;
        int c2 = c1 + 1; if (c2 == 3) c2 = 0;
        float4 s = src4[i];
        float4 t = tgt4[i];
        atomicAdd(&lh[c0 * NBINS + binof(s.x)], 1);
        atomicAdd(&lh[c1 * NBINS + binof(s.y)], 1);
        atomicAdd(&lh[c2 * NBINS + binof(s.z)], 1);
        atomicAdd(&lh[c0 * NBINS + binof(s.w)], 1);
        atomicAdd(&lh[(3 + c0) * NBINS + binof(t.x)], 1);
        atomicAdd(&lh[(3 + c1) * NBINS + binof(t.y)], 1);
        atomicAdd(&lh[(3 + c2) * NBINS + binof(t.z)], 1);
        atomicAdd(&lh[(3 + c0) * NBINS + binof(t.w)], 1);
    }
    // scalar tail (n not divisible by 4)
    if (blockIdx.x == 0) {
        int base = n4 * 4;
        int rem = n - base;
        if ((int)threadIdx.x < rem) {
            int j = base + threadIdx.x;
            int c = j % 3;
            atomicAdd(&lh[c * NBINS + binof(src[j])], 1);
            atomicAdd(&lh[(3 + c) * NBINS + binof(tgt[j])], 1);
        }
    }
    __syncthreads();

    int* dst = partials + blockIdx.x * SLOT;
    for (int i = threadIdx.x; i < 6 * NBINS; i += blockDim.x) dst[i] = lh[i];
}

// ---------------------------------------------------------------------------
// Kernel 1.5: parallel level-1 reduction of 256 partial slots -> 16 slots
// (in-place: result for group k lands in slot 16*k). Block b: h = b/16
// (histogram 0..5), k = b%16 (group). Each thread sums 16 independent loads.
// Safe in-place: location [16k][h][t] is read+written only by thread (h,k,t).
// ---------------------------------------------------------------------------
__global__ void hm_reduce(int* __restrict__ partials) {
    int h = blockIdx.x >> 4;    // 0..5
    int k = blockIdx.x & 15;    // 0..15
    int t = threadIdx.x;
    int base = (k * 16) * SLOT + h * NBINS + t;
    int s = 0;
    #pragma unroll
    for (int j = 0; j < 16; j++) s += partials[base + j * SLOT];
    partials[base] = s;
}

// ---------------------------------------------------------------------------
// Kernel 2: per-channel (blockIdx.x = channel): reduce nslots slots (spaced
// step apart) -> cumsum -> cdfsrc/cdftgt -> pxmap = _interpolate(cdftgt, cs,
// cdfsrc). 256 threads = 256 bins.
// ---------------------------------------------------------------------------
__global__ void hm_tables(const int* __restrict__ partials, int nslots, int step,
                          float pixcnt_m1, float* __restrict__ pxmap) {
    const int c = blockIdx.x;
    const int t = threadIdx.x;
    __shared__ int ss[NBINS];
    __shared__ int st[NBINS];
    __shared__ float cdfs[NBINS];
    __shared__ float cdft[NBINS];

    int as = 0, at = 0;
    for (int b = 0; b < nslots; b++) {
        const int* p = partials + (b * step) * SLOT;
        as += p[c * NBINS + t];
        at += p[(3 + c) * NBINS + t];
    }
    ss[t] = as;
    st[t] = at;
    __syncthreads();

    // Hillis-Steele inclusive scan (both histograms)
    for (int off = 1; off < NBINS; off <<= 1) {
        int a = (t >= off) ? ss[t - off] : 0;
        int b = (t >= off) ? st[t - off] : 0;
        __syncthreads();
        ss[t] += a;
        st[t] += b;
        __syncthreads();
    }

    // cdf nondecreasing -> min = cdf[0]; exact ref op order
    int mins = ss[0];
    int mint = st[0];
    cdfs[t] = (float)(ss[t] - mins) * 2.0f / pixcnt_m1 - 1.0f;
    cdft[t] = (float)(st[t] - mint) * 2.0f / pixcnt_m1 - 1.0f;
    __syncthreads();

    // pxmap[t] = _interpolate(dx=cdftgt, dy=cs, x=cdfsrc[t]); first-min argmin
    float x = cdfs[t];
    int ind1 = 0;
    float best = fabsf(cdft[0] - x);
    for (int i = 1; i < NBINS; i++) {
        float d = fabsf(cdft[i] - x);
        if (d < best) { best = d; ind1 = i; }
    }
    int ind0 = max(ind1 - 1, 0);
    float x0 = cdft[ind0], x1 = cdft[ind1];
    float y0 = csv(ind0),  y1 = csv(ind1);
    float denom = x1 - x0;
    float safe = (denom == 0.0f) ? 1.0f : denom;
    float interp = y0 + (y1 - y0) * (x - x0) / safe;

    float r;
    if (x <= cdft[0])            r = csv(0);
    else if (x >= cdft[NBINS-1]) r = csv(NBINS - 1);
    else                         r = interp;

    pxmap[c * NBINS + t] = r;
}

// ---------------------------------------------------------------------------
// Kernel 3: mapped = _interpolate(dx=cs, dy=pxmap[c], x=src). float4 I/O.
// ---------------------------------------------------------------------------
__device__ __forceinline__ float map_one(float x, const float* __restrict__ y) {
    if (x <= -1.0f) return y[0];
    if (x >= 1.0f)  return y[NBINS - 1];
    float kf = (x + 1.0f) * 127.0f;
    int k = (int)(kf + 0.5f);
    int lo = max(k - 1, 0);
    int hi = min(k + 1, NBINS - 1);
    int ind1 = lo;
    float best = fabsf(csv(lo) - x);
    for (int j = lo + 1; j <= hi; j++) {
        float d = fabsf(csv(j) - x);
        if (d < best) { best = d; ind1 = j; }
    }
    int ind0 = max(ind1 - 1, 0);
    float x0 = csv(ind0), x1 = csv(ind1);
    float y0 = y[ind0],   y1 = y[ind1];
    float denom = x1 - x0;
    float safe = (denom == 0.0f) ? 1.0f : denom;
    return y0 + (y1 - y0) * (x - x0) / safe;
}

__global__ void hm_map(const float4* __restrict__ src4, const float* __restrict__ src,
                       const float* __restrict__ pxmap,
                       float4* __restrict__ out4, float* __restrict__ out,
                       int n4, int n) {
    __shared__ float pm[3 * NBINS];
    for (int i = threadIdx.x; i < 3 * NBINS; i += blockDim.x) pm[i] = pxmap[i];
    __syncthreads();

    const int stride = gridDim.x * blockDim.x;
    for (int i = blockIdx.x * blockDim.x + threadIdx.x; i < n4; i += stride) {
        int c0 = i % 3;
        int c1 = c0 + 1; if (c1 == 3) c1 = 0;
        int c2 = c1 + 1; if (c2 == 3) c2 = 0;
        float4 s = src4[i];
        float4 r;
        r.x = map_one(s.x, &pm[c0 * NBINS]);
        r.y = map_one(s.y, &pm[c1 * NBINS]);
        r.z = map_one(s.z, &pm[c2 * NBINS]);
        r.w = map_one(s.w, &pm[c0 * NBINS]);
        out4[i] = r;
    }
    // scalar tail
    if (blockIdx.x == 0) {
        int base = n4 * 4;
        int rem = n - base;
        if ((int)threadIdx.x < rem) {
            int j = base + threadIdx.x;
            int c = j % 3;
            out[j] = map_one(src[j], &pm[c * NBINS]);
        }
    }
}

extern "C" void kernel_launch(void* const* d_in, const int* in_sizes, int n_in,
                              void* d_out, int out_size, void* d_ws, size_t ws_size,
                              hipStream_t stream) {
    const float* src = (const float*)d_in[0];
    const float* tgt = (const float*)d_in[1];
    float* out = (float*)d_out;

    const int n  = in_sizes[0];     // H*W*3
    const int n4 = n / 4;
    const int pixcnt = n / 3;       // H*W

    // ws layout: [0, 4096): pxmap (3*256 floats); [4096, ...): partials
    float* pxmap    = (float*)d_ws;
    int*   partials = (int*)((char*)d_ws + 4096);

    const int slot_bytes = SLOT * (int)sizeof(int);   // 6 KiB per slot
    int NB = 256;
    if (ws_size >= 4096 + (size_t)slot_bytes) {
        size_t avail = (ws_size - 4096) / slot_bytes;
        if (avail < (size_t)NB) NB = (int)avail;
    } else {
        NB = 1;  // degenerate but correct
    }

    hm_hist<<<NB, 1024, 0, stream>>>((const float4*)src, (const float4*)tgt,
                                     src, tgt, n4, n, partials);

    if (NB == 256) {
        // level-1 reduce: 256 slots -> 16 slots (at indices 0,16,...,240)
        hm_reduce<<<96, NBINS, 0, stream>>>(partials);
        hm_tables<<<3, NBINS, 0, stream>>>(partials, 16, 16,
                                           (float)pixcnt - 1.0f, pxmap);
    } else {
        hm_tables<<<3, NBINS, 0, stream>>>(partials, NB, 1,
                                           (float)pixcnt - 1.0f, pxmap);
    }

    int mblocks = (n4 + 255) / 256;
    if (mblocks > 3072) mblocks = 3072;
    if (mblocks < 1) mblocks = 1;
    hm_map<<<mblocks, 256, 0, stream>>>((const float4*)src, src, pxmap,
                                        (float4*)out, out, n4, n);
}